// Round 1
// baseline (374.330 us; speedup 1.0000x reference)
//
#include <hip/hip_runtime.h>

#define KH 18          // total harmonics
#define NPTS (128*128*128)
#define BB 4           // batch
#define BLK 256

// No LDS at all: trig tables replaced by Chebyshev 3-term recurrence
// (c_{k+1} = 2cos(th)*c_k - c_{k-1}), fa/fb staged directly per-thread as
// float2 (rows are 72B, 8B-aligned). launch_bounds(256,8) targets 64 VGPR
// -> 8 waves/SIMD, 32 waves/CU.
__global__ __launch_bounds__(BLK, 8) void dddm_kernel(
    const float* __restrict__ input_t,
    const float* __restrict__ poly,    // [N,4]
    const float* __restrict__ fa,      // [N,18]
    const float* __restrict__ fb,      // [N,18]
    const int*   __restrict__ stage_p,
    float* __restrict__ out)           // [2,B,N] concat: y_poly then y_fourier
{
    const int tid = threadIdx.x;
    const int n   = blockIdx.x * BLK + tid;

    // ---- uniform per-batch seeds (scalar loads; sincosf once per batch) ----
    float tb[BB], c1[BB], s1[BB], d[BB];
#pragma unroll
    for (int b = 0; b < BB; ++b) {
        const float t = input_t[b];
        tb[b] = t;
        float sn, cs;
        sincosf(6.283185307179586f * t, &sn, &cs);
        c1[b] = cs; s1[b] = sn; d[b] = 2.0f * cs;
    }

    // stage gating (wave-uniform scalar)
    const int ms = *stage_p;
    const int cs_ = (ms >= 0) ? (ms < 3 ? ms : 3) : 3;
    const int kmax = (cs_ >= 3) ? 18 : (cs_ == 2 ? 9 : (cs_ == 1 ? 3 : 0));

    // ---- polynomial: row is 16B, 16B-aligned -> float4 + Horner ----
    const float4 c4 = reinterpret_cast<const float4*>(poly)[n];
    float yp[BB], yf[BB];
#pragma unroll
    for (int b = 0; b < BB; ++b) {
        const float t = tb[b];
        yp[b] = ((c4.w * t + c4.z) * t + c4.y) * t + c4.x;
        yf[b] = 0.0f;
    }

    // ---- fourier: direct per-thread row loads (9x float2 each) ----
    const float2* ar = reinterpret_cast<const float2*>(fa + (size_t)n * KH);
    const float2* br = reinterpret_cast<const float2*>(fb + (size_t)n * KH);

    if (kmax == KH) {
        // trig recurrence state per batch: cos(k*th), sin(k*th)
        float cc[BB], ss[BB], cp[BB], sp[BB];
#pragma unroll
        for (int b = 0; b < BB; ++b) {
            cc[b] = c1[b]; ss[b] = s1[b];   // k = 1
            cp[b] = 1.0f;  sp[b] = 0.0f;    // k = 0
        }
#pragma unroll
        for (int j = 0; j < 9; ++j) {
            const float2 a2 = ar[j];
            const float2 b2 = br[j];
#pragma unroll
            for (int u = 0; u < 2; ++u) {
                const float ak = u ? a2.y : a2.x;
                const float bk = u ? b2.y : b2.x;
#pragma unroll
                for (int b = 0; b < BB; ++b) {
                    yf[b] += ak * cc[b];
                    yf[b] += bk * ss[b];
                    const float cn = __builtin_fmaf(d[b], cc[b], -cp[b]);
                    const float s2 = __builtin_fmaf(d[b], ss[b], -sp[b]);
                    cp[b] = cc[b]; sp[b] = ss[b];
                    cc[b] = cn;    ss[b] = s2;
                }
            }
        }
    } else if (kmax > 0) {
        // rare path (stage < 3): scalar per-k loads, dynamic trip count
        const float* arow = fa + (size_t)n * KH;
        const float* brow = fb + (size_t)n * KH;
        float cc[BB], ss[BB], cp[BB], sp[BB];
#pragma unroll
        for (int b = 0; b < BB; ++b) {
            cc[b] = c1[b]; ss[b] = s1[b];
            cp[b] = 1.0f;  sp[b] = 0.0f;
        }
        for (int k = 0; k < kmax; ++k) {
            const float ak = arow[k];
            const float bk = brow[k];
#pragma unroll
            for (int b = 0; b < BB; ++b) {
                yf[b] += ak * cc[b];
                yf[b] += bk * ss[b];
                const float cn = __builtin_fmaf(d[b], cc[b], -cp[b]);
                const float s2 = __builtin_fmaf(d[b], ss[b], -sp[b]);
                cp[b] = cc[b]; sp[b] = ss[b];
                cc[b] = cn;    ss[b] = s2;
            }
        }
    }

    // ---- store: coalesced dword per (output, b) plane ----
#pragma unroll
    for (int b = 0; b < BB; ++b) {
        out[(size_t)b * NPTS + n]        = yp[b];
        out[(size_t)(BB + b) * NPTS + n] = yf[b];
    }
}

extern "C" void kernel_launch(void* const* d_in, const int* in_sizes, int n_in,
                              void* d_out, int out_size, void* d_ws, size_t ws_size,
                              hipStream_t stream) {
    const float* input_t = (const float*)d_in[0];
    const float* poly    = (const float*)d_in[1];
    const float* fa      = (const float*)d_in[2];
    const float* fb      = (const float*)d_in[3];
    const int*   stage   = (const int*)d_in[4];
    float* out = (float*)d_out;

    dddm_kernel<<<NPTS / BLK, BLK, 0, stream>>>(input_t, poly, fa, fb, stage, out);
}